// Round 7
// baseline (49.222 us; speedup 1.0000x reference)
//
#include <hip/hip_runtime.h>
#include <math.h>

// densemap = sum_k c_k * log2(relu(k^2 * conv_k(x)) + 1)
// conv_k = separable Gaussian (sigma = k/2), TF-SAME padding: pad_lo = (k-1)/2.
// Column/row window offsets union: -2..+3 (6 wide). k=1 kernel == identity.
//
// Persistent-strip 2-phase pipeline: each block owns a 64-col x 256-row strip,
// marching in 8 steps of 32 rows. Step t issues global_load_lds staging for
// step t+1 into LDS buffer (t+1)&1, computes step t from buffer t&1, then one
// __syncthreads(). The barrier's implicit vmcnt(0) drain is harmless: the
// drained loads were issued a full compute-phase earlier (T3 minimum-2-phase).
// Grid 8x2x64 = 1024 blocks = 4 blocks/CU; 4 waves/SIMD from 4 independent
// blocks cover each other's barrier stalls.

struct Weights {
    // symmetric-pair horizontal coefficients (prescaled by k^2)
    float h2, h3a, h3b, h4a, h4b, h5a, h5b, h5c, h6a, h6b, h6c;
    float wv[6][6]; // vertical 1D gaussian weights
    float c[6];     // regression slope coefficients
};

#define TXO 64
#define STEP 32         // output rows per pipeline step
#define RPT 8           // rows per thread per step (block 64x4)
#define LDSW 72         // floats per staged row (16B-aligned stride)
#define SROWS 37        // staged rows per step: outputs -2..+34
#define NF4 (SROWS * 18)  // 666 float4s per staged tile

#define GLOAD_LDS16(gp, lp) __builtin_amdgcn_global_load_lds( \
    (const __attribute__((address_space(1))) unsigned int*)(gp), \
    (__attribute__((address_space(3))) unsigned int*)(lp), 16, 0, 0)

__global__ __launch_bounds__(256, 4) void ldeb_kernel(const float* __restrict__ x,
                                                      float* __restrict__ out,
                                                      Weights W) {
    __shared__ float xs[2][SROWS * LDSW];
    const int img = blockIdx.z;
    const int bx = blockIdx.x;
    const int ybase = blockIdx.y * 256;      // this block's strip: 256 rows
    const int x0a = bx * TXO - 4;            // aligned staged-col base
    const float* __restrict__ xb = x + (size_t)img * 262144;
    const int tid = threadIdx.y * 64 + threadIdx.x;

    // stage 37 rows x 72 cols starting at global row y0 into LDS buffer `buf`
    auto stage = [&](int buf, int y0, bool guard) {
        if (!guard) {
            // interior: direct global->LDS, 16B/lane, dest linear in tid
#pragma unroll
            for (int it = 0; it < 3; ++it) {
                int i = tid + it * 256;
                if (i < NF4) {
                    int row = i / 18;
                    int c4 = i - row * 18;
                    const float* gp = xb + (size_t)(y0 + row) * 512 + x0a + 4 * c4;
                    GLOAD_LDS16(gp, &xs[buf][i * 4]);
                }
            }
        } else {
            // border: reg-staged float4 with whole-float4 zero-fill
#pragma unroll
            for (int it = 0; it < 3; ++it) {
                int i = tid + it * 256;
                if (i < NF4) {
                    int row = i / 18;
                    int c4 = i - row * 18;
                    int gy = y0 + row;
                    int gc = x0a + 4 * c4;
                    float4 v = make_float4(0.f, 0.f, 0.f, 0.f);
                    if ((unsigned)gy < 512u && (unsigned)gc < 512u)
                        v = *(const float4*)(xb + (size_t)gy * 512 + gc);
                    *(float4*)&xs[buf][i * 4] = v;
                }
            }
        }
    };

    const bool xguard = (bx == 0) || (bx == 7);

    // prologue: stage step 0
    stage(0, ybase - 2, xguard || (ybase - 2 < 0));
    __syncthreads();

    const int lc = threadIdx.x;          // local col 0..63
    const int Lr0 = threadIdx.y * RPT;   // this thread's row base within a step

    float Hr[6][6];  // 6-deep ring; all indices are ICEs -> VGPRs

// horizontal pass, symmetric-pair form: 5 adds + 11 mul/fma
#define HROW(i) { \
        const float* row = base + (i) * LDSW; \
        float v0 = row[0], v1 = row[1], v2 = row[2], \
              v3 = row[3], v4 = row[4], v5 = row[5]; \
        float s23 = v2 + v3, s14 = v1 + v4, s05 = v0 + v5; \
        float s13 = v1 + v3, s04 = v0 + v4; \
        Hr[(i) % 6][0] = v2; /* k=1: identity */ \
        Hr[(i) % 6][1] = W.h2  * s23; \
        Hr[(i) % 6][2] = W.h3a * s13 + W.h3b * v2; \
        Hr[(i) % 6][3] = W.h4a * s14 + W.h4b * s23; \
        Hr[(i) % 6][4] = W.h5a * s04 + W.h5b * s13 + W.h5c * v2; \
        Hr[(i) % 6][5] = W.h6a * s05 + W.h6b * s14 + W.h6c * s23; \
    }
#define SLOT(n) Hr[(n) % 6]

// vertical pass + log + slope for output row r (pad_lo per k: 0,0,1,1,2,2)
#define VPASS(r) { \
        float s1 = SLOT((r) + 2)[0]; \
        float s2 = SLOT((r) + 2)[1] * W.wv[1][0] + SLOT((r) + 3)[1] * W.wv[1][1]; \
        float s3 = SLOT((r) + 1)[2] * W.wv[2][0] + SLOT((r) + 2)[2] * W.wv[2][1] \
                 + SLOT((r) + 3)[2] * W.wv[2][2]; \
        float s4 = SLOT((r) + 1)[3] * W.wv[3][0] + SLOT((r) + 2)[3] * W.wv[3][1] \
                 + SLOT((r) + 3)[3] * W.wv[3][2] + SLOT((r) + 4)[3] * W.wv[3][3]; \
        float s5 = SLOT((r) + 0)[4] * W.wv[4][0] + SLOT((r) + 1)[4] * W.wv[4][1] \
                 + SLOT((r) + 2)[4] * W.wv[4][2] + SLOT((r) + 3)[4] * W.wv[4][3] \
                 + SLOT((r) + 4)[4] * W.wv[4][4]; \
        float s6 = SLOT((r) + 0)[5] * W.wv[5][0] + SLOT((r) + 1)[5] * W.wv[5][1] \
                 + SLOT((r) + 2)[5] * W.wv[5][2] + SLOT((r) + 3)[5] * W.wv[5][3] \
                 + SLOT((r) + 4)[5] * W.wv[5][4] + SLOT((r) + 5)[5] * W.wv[5][5]; \
        float y1 = __builtin_amdgcn_logf(fmaxf(s1, 0.0f) + 1.0f); \
        float y2 = __builtin_amdgcn_logf(fmaxf(s2, 0.0f) + 1.0f); \
        float y3 = __builtin_amdgcn_logf(fmaxf(s3, 0.0f) + 1.0f); \
        float y4 = __builtin_amdgcn_logf(fmaxf(s4, 0.0f) + 1.0f); \
        float y5 = __builtin_amdgcn_logf(fmaxf(s5, 0.0f) + 1.0f); \
        float y6 = __builtin_amdgcn_logf(fmaxf(s6, 0.0f) + 1.0f); \
        ob[(r) * 512] = W.c[0] * y1 + W.c[1] * y2 + W.c[2] * y3 \
                      + W.c[3] * y4 + W.c[4] * y5 + W.c[5] * y6; \
    }

#define ITER(r) HROW((r) + 5) VPASS(r)

    float* __restrict__ ob0 = out + (size_t)img * 262144
                            + (size_t)(ybase + Lr0) * 512 + bx * TXO + lc;

    for (int t = 0; t < 8; ++t) {
        // issue staging for step t+1 (lands during this step's compute)
        if (t < 7) {
            int y0n = ybase + (t + 1) * STEP - 2;
            stage((t + 1) & 1, y0n, xguard || (y0n + SROWS - 1 > 511));
        }

        const float* __restrict__ base = &xs[t & 1][Lr0 * LDSW + lc + 2];
        float* __restrict__ ob = ob0 + (size_t)t * STEP * 512;

        // prologue rows of this step's window
        HROW(0) HROW(1) HROW(2) HROW(3) HROW(4)
        // straight-line body: every ring index an integer constant expression
        ITER(0) ITER(1) ITER(2) ITER(3)
        ITER(4) ITER(5) ITER(6) ITER(7)

        __syncthreads();
    }

#undef ITER
#undef VPASS
#undef HROW
#undef SLOT
}

extern "C" void kernel_launch(void* const* d_in, const int* in_sizes, int n_in,
                              void* d_out, int out_size, void* d_ws, size_t ws_size,
                              hipStream_t stream) {
    const float* x = (const float*)d_in[0];
    float* out = (float*)d_out;

    Weights W;
    // regression coefficients: c_k = (X_k - mean(X)) / sum((X - mean)^2), X_k = log2(k)
    double X[6], mean = 0.0;
    for (int k = 1; k <= 6; ++k) { X[k - 1] = log2((double)k); mean += X[k - 1]; }
    mean /= 6.0;
    double denom = 0.0;
    for (int i = 0; i < 6; ++i) { double xc = X[i] - mean; denom += xc * xc; }
    for (int i = 0; i < 6; ++i) W.c[i] = (float)((X[i] - mean) / denom);

    // separable gaussian 1D weights, sigma = k/2
    float wh[6][6];
    for (int k = 1; k <= 6; ++k) {
        double sigma = k / 2.0;
        double g[6], s = 0.0;
        for (int i = 0; i < k; ++i) {
            double a = i - (k - 1) / 2.0;
            g[i] = exp(-(a * a) / (2.0 * sigma * sigma));
            s += g[i];
        }
        for (int i = 0; i < 6; ++i) {
            if (i < k) {
                double gn = g[i] / s;
                W.wv[k - 1][i] = (float)gn;
                wh[k - 1][i] = (float)(gn * (double)(k * k)); // horizontal prescaled by k^2
            } else {
                W.wv[k - 1][i] = 0.0f;
                wh[k - 1][i] = 0.0f;
            }
        }
    }
    // symmetric-pair horizontal coefficients
    W.h2  = wh[1][0];
    W.h3a = wh[2][0]; W.h3b = wh[2][1];
    W.h4a = wh[3][0]; W.h4b = wh[3][1];
    W.h5a = wh[4][0]; W.h5b = wh[4][1]; W.h5c = wh[4][2];
    W.h6a = wh[5][0]; W.h6b = wh[5][1]; W.h6c = wh[5][2];

    dim3 grid(512 / TXO, 2, 64);
    dim3 block(64, 4, 1);
    hipLaunchKernelGGL(ldeb_kernel, grid, block, 0, stream, x, out, W);
}

// Round 8
// 47.486 us; speedup vs baseline: 1.0366x; 1.0366x over previous
//
#include <hip/hip_runtime.h>
#include <math.h>

// densemap = sum_k c_k * log2(relu(k^2 * conv_k(x)) + 1)
// conv_k = separable Gaussian (sigma = k/2), TF-SAME padding: pad_lo = (k-1)/2.
// Column/row window offsets union: -2..+3 (6 wide). k=1 kernel == identity.
//
// BARRIER-FREE wave-autonomous design: each wave owns a 64-col x 8-row output
// strip and a PRIVATE 13-row x 72-col LDS region (3.7 KB). It stages its own
// rows with global_load_lds, does a wave-level s_waitcnt vmcnt(0) (inline asm
// -- no __syncthreads anywhere), and computes. 8 blocks/CU x 4 waves = 32
// independent {stage -> wait -> compute} chains per CU for latency hiding.
// Row overlap between adjacent waves is refetched but L2-hot (same CU/XCD).

struct Weights {
    // symmetric-pair horizontal coefficients (prescaled by k^2)
    float h2, h3a, h3b, h4a, h4b, h5a, h5b, h5c, h6a, h6b, h6c;
    float wv[6][6]; // vertical 1D gaussian weights
    float c[6];     // regression slope coefficients
};

#define LDSW 72          // floats per staged row (16B-aligned stride)
#define WROWS 13         // rows staged per wave: outputs -2..+10
#define WF4 (WROWS * 18) // 234 float4s per wave region

#define GLOAD_LDS16(gp, lp) __builtin_amdgcn_global_load_lds( \
    (const __attribute__((address_space(1))) unsigned int*)(gp), \
    (__attribute__((address_space(3))) unsigned int*)(lp), 16, 0, 0)

__global__ __launch_bounds__(256, 8) void ldeb_kernel(const float* __restrict__ x,
                                                      float* __restrict__ out,
                                                      Weights W) {
    __shared__ float xs[4][WROWS * LDSW];   // 4 private wave regions, 15 KB
    const int img = blockIdx.z;
    const int bx = blockIdx.x;
    const int ty = threadIdx.y;              // wave id 0..3
    const int lane = threadIdx.x;            // 0..63
    const int R0 = blockIdx.y * 32 + ty * 8; // this wave's first output row
    const int gy0 = R0 - 2;                  // first staged row
    const int x0a = bx * 64 - 4;             // aligned staged-col base
    const float* __restrict__ xb = x + (size_t)img * 262144;
    float* __restrict__ lbase = xs[ty];

    const bool guard = (bx == 0) | (bx == 7) | (gy0 < 0) | (gy0 + 12 > 511);

    if (!guard) {
        // interior wave: direct global->LDS, 16B/lane, dest linear in lane
#pragma unroll
        for (int it = 0; it < 4; ++it) {
            int idx = lane + it * 64;
            if (idx < WF4) {
                int row = idx / 18;
                int c4 = idx - row * 18;
                const float* gp = xb + (size_t)(gy0 + row) * 512 + x0a + 4 * c4;
                GLOAD_LDS16(gp, &lbase[idx * 4]);
            }
        }
    } else {
        // border wave: reg-staged float4 with whole-float4 zero-fill
#pragma unroll
        for (int it = 0; it < 4; ++it) {
            int idx = lane + it * 64;
            if (idx < WF4) {
                int row = idx / 18;
                int c4 = idx - row * 18;
                int gy = gy0 + row;
                int gc = x0a + 4 * c4;
                float4 v = make_float4(0.f, 0.f, 0.f, 0.f);
                if ((unsigned)gy < 512u && (unsigned)gc < 512u)
                    v = *(const float4*)(xb + (size_t)gy * 512 + gc);
                *(float4*)&lbase[idx * 4] = v;
            }
        }
    }
    // wave-level drain of this wave's own global_load_lds; NO block barrier
    asm volatile("s_waitcnt vmcnt(0)" ::: "memory");

    const float* __restrict__ base = &lbase[lane + 2];

    float Hr[6][6];  // 6-deep ring; all indices are ICEs -> VGPRs

// horizontal pass, symmetric-pair form: 5 adds + 11 mul/fma
#define HROW(i) { \
        const float* row = base + (i) * LDSW; \
        float v0 = row[0], v1 = row[1], v2 = row[2], \
              v3 = row[3], v4 = row[4], v5 = row[5]; \
        float s23 = v2 + v3, s14 = v1 + v4, s05 = v0 + v5; \
        float s13 = v1 + v3, s04 = v0 + v4; \
        Hr[(i) % 6][0] = v2; /* k=1: identity */ \
        Hr[(i) % 6][1] = W.h2  * s23; \
        Hr[(i) % 6][2] = W.h3a * s13 + W.h3b * v2; \
        Hr[(i) % 6][3] = W.h4a * s14 + W.h4b * s23; \
        Hr[(i) % 6][4] = W.h5a * s04 + W.h5b * s13 + W.h5c * v2; \
        Hr[(i) % 6][5] = W.h6a * s05 + W.h6b * s14 + W.h6c * s23; \
    }
#define SLOT(n) Hr[(n) % 6]

// vertical pass + log + slope for output row r (pad_lo per k: 0,0,1,1,2,2)
#define VPASS(r) { \
        float s1 = SLOT((r) + 2)[0]; \
        float s2 = SLOT((r) + 2)[1] * W.wv[1][0] + SLOT((r) + 3)[1] * W.wv[1][1]; \
        float s3 = SLOT((r) + 1)[2] * W.wv[2][0] + SLOT((r) + 2)[2] * W.wv[2][1] \
                 + SLOT((r) + 3)[2] * W.wv[2][2]; \
        float s4 = SLOT((r) + 1)[3] * W.wv[3][0] + SLOT((r) + 2)[3] * W.wv[3][1] \
                 + SLOT((r) + 3)[3] * W.wv[3][2] + SLOT((r) + 4)[3] * W.wv[3][3]; \
        float s5 = SLOT((r) + 0)[4] * W.wv[4][0] + SLOT((r) + 1)[4] * W.wv[4][1] \
                 + SLOT((r) + 2)[4] * W.wv[4][2] + SLOT((r) + 3)[4] * W.wv[4][3] \
                 + SLOT((r) + 4)[4] * W.wv[4][4]; \
        float s6 = SLOT((r) + 0)[5] * W.wv[5][0] + SLOT((r) + 1)[5] * W.wv[5][1] \
                 + SLOT((r) + 2)[5] * W.wv[5][2] + SLOT((r) + 3)[5] * W.wv[5][3] \
                 + SLOT((r) + 4)[5] * W.wv[5][4] + SLOT((r) + 5)[5] * W.wv[5][5]; \
        float y1 = __builtin_amdgcn_logf(fmaxf(s1, 0.0f) + 1.0f); \
        float y2 = __builtin_amdgcn_logf(fmaxf(s2, 0.0f) + 1.0f); \
        float y3 = __builtin_amdgcn_logf(fmaxf(s3, 0.0f) + 1.0f); \
        float y4 = __builtin_amdgcn_logf(fmaxf(s4, 0.0f) + 1.0f); \
        float y5 = __builtin_amdgcn_logf(fmaxf(s5, 0.0f) + 1.0f); \
        float y6 = __builtin_amdgcn_logf(fmaxf(s6, 0.0f) + 1.0f); \
        ob[(r) * 512] = W.c[0] * y1 + W.c[1] * y2 + W.c[2] * y3 \
                      + W.c[3] * y4 + W.c[4] * y5 + W.c[5] * y6; \
    }

#define ITER(r) HROW((r) + 5) VPASS(r)

    float* __restrict__ ob = out + (size_t)img * 262144
                           + (size_t)R0 * 512 + bx * 64 + lane;

    // prologue: staged rows 0..4 of this wave's window
    HROW(0) HROW(1) HROW(2) HROW(3) HROW(4)
    // straight-line body: every ring index an integer constant expression
    ITER(0) ITER(1) ITER(2) ITER(3)
    ITER(4) ITER(5) ITER(6) ITER(7)

#undef ITER
#undef VPASS
#undef HROW
#undef SLOT
}

extern "C" void kernel_launch(void* const* d_in, const int* in_sizes, int n_in,
                              void* d_out, int out_size, void* d_ws, size_t ws_size,
                              hipStream_t stream) {
    const float* x = (const float*)d_in[0];
    float* out = (float*)d_out;

    Weights W;
    // regression coefficients: c_k = (X_k - mean(X)) / sum((X - mean)^2), X_k = log2(k)
    double X[6], mean = 0.0;
    for (int k = 1; k <= 6; ++k) { X[k - 1] = log2((double)k); mean += X[k - 1]; }
    mean /= 6.0;
    double denom = 0.0;
    for (int i = 0; i < 6; ++i) { double xc = X[i] - mean; denom += xc * xc; }
    for (int i = 0; i < 6; ++i) W.c[i] = (float)((X[i] - mean) / denom);

    // separable gaussian 1D weights, sigma = k/2
    float wh[6][6];
    for (int k = 1; k <= 6; ++k) {
        double sigma = k / 2.0;
        double g[6], s = 0.0;
        for (int i = 0; i < k; ++i) {
            double a = i - (k - 1) / 2.0;
            g[i] = exp(-(a * a) / (2.0 * sigma * sigma));
            s += g[i];
        }
        for (int i = 0; i < 6; ++i) {
            if (i < k) {
                double gn = g[i] / s;
                W.wv[k - 1][i] = (float)gn;
                wh[k - 1][i] = (float)(gn * (double)(k * k)); // horizontal prescaled by k^2
            } else {
                W.wv[k - 1][i] = 0.0f;
                wh[k - 1][i] = 0.0f;
            }
        }
    }
    // symmetric-pair horizontal coefficients
    W.h2  = wh[1][0];
    W.h3a = wh[2][0]; W.h3b = wh[2][1];
    W.h4a = wh[3][0]; W.h4b = wh[3][1];
    W.h5a = wh[4][0]; W.h5b = wh[4][1]; W.h5c = wh[4][2];
    W.h6a = wh[5][0]; W.h6b = wh[5][1]; W.h6c = wh[5][2];

    dim3 grid(8, 16, 64);
    dim3 block(64, 4, 1);
    hipLaunchKernelGGL(ldeb_kernel, grid, block, 0, stream, x, out, W);
}

// Round 9
// 46.896 us; speedup vs baseline: 1.0496x; 1.0126x over previous
//
#include <hip/hip_runtime.h>
#include <math.h>

// densemap = sum_k c_k * log2(relu(k^2 * conv_k(x)) + 1)
// conv_k = separable Gaussian (sigma = k/2), TF-SAME padding: pad_lo = (k-1)/2.
// Column/row window offsets union: -2..+3 (6 wide). k=1 kernel == identity.
//
// Tile: 64x32 outputs per block (block 64x4, 8 rows/wave), staged 37x72 LDS.
// COMPUTE IS SPLIT INTO 3 PASSES over kernel pairs {6,5},{4,3},{2,1} so the
// per-pass live set (ring 6+5 + 8 accumulators + transients ~ 30 floats) fits
// the 8-wave/SIMD 64-register tier -- the previous single-pass 36-float ring
// could not live in the reported 24 VGPRs and was being shuttled through
// AGPRs/remat, costing ~+60 VALU cyc/output (the persistent 2x VALU bloat).

struct Weights {
    // horizontal symmetric-pair coefficients (prescaled by k^2)
    float h6a, h6b, h6c, h5a, h5b, h5c, h4a, h4b, h3a, h3b, h2c;
    // vertical symmetric-pair coefficients
    float v6a, v6b, v6c, v5a, v5b, v5c, v4a, v4b, v3a, v3b, v2a;
    float c[6];     // regression slope coefficients
};

#define TXO 64
#define TYO 32
#define RPT 8           // rows per thread (block 64x4)
#define LDSW 72         // floats per staged row (16B-aligned stride)
#define SROWS 37        // staged rows: outputs -2..+34
#define NF4 (SROWS * 18)  // 666 float4s per tile

#define GLOAD_LDS16(gp, lp) __builtin_amdgcn_global_load_lds( \
    (const __attribute__((address_space(1))) unsigned int*)(gp), \
    (__attribute__((address_space(3))) unsigned int*)(lp), 16, 0, 0)

__global__ __launch_bounds__(256, 8) void ldeb_kernel(const float* __restrict__ x,
                                                      float* __restrict__ out,
                                                      Weights W) {
    __shared__ float xs[SROWS * LDSW];
    const int img = blockIdx.z;
    const int bx = blockIdx.x, by = blockIdx.y;
    const int x0a = bx * TXO - 4;      // aligned staged-col base
    const int y0 = by * TYO - 2;       // staged-row base
    const float* __restrict__ xb = x + (size_t)img * 262144;
    const int tid = threadIdx.y * 64 + threadIdx.x;

    if (bx >= 1 && bx <= 6 && by >= 1 && by <= 14) {
        // interior: direct global->LDS, 16B/lane, dest linear in tid
#pragma unroll
        for (int it = 0; it < 3; ++it) {
            int i = tid + it * 256;
            if (i < NF4) {
                int row = i / 18;
                int c4 = i - row * 18;
                const float* gp = xb + (size_t)(y0 + row) * 512 + x0a + 4 * c4;
                GLOAD_LDS16(gp, &xs[i * 4]);
            }
        }
    } else {
        // border: reg-staged float4 with whole-float4 zero-fill
#pragma unroll
        for (int it = 0; it < 3; ++it) {
            int i = tid + it * 256;
            if (i < NF4) {
                int row = i / 18;
                int c4 = i - row * 18;
                int gy = y0 + row;
                int gc = x0a + 4 * c4;
                float4 v = make_float4(0.f, 0.f, 0.f, 0.f);
                if ((unsigned)gy < 512u && (unsigned)gc < 512u)
                    v = *(const float4*)(xb + (size_t)gy * 512 + gc);
                *(float4*)&xs[i * 4] = v;
            }
        }
    }
    __syncthreads();

    const int lane = threadIdx.x;        // local col 0..63
    const int Lr0 = threadIdx.y * RPT;   // this wave's staged-row base
    // staged col for tap offset -2 of output col (bx*64+lane) is lane+2
    const float* __restrict__ base = &xs[Lr0 * LDSW + lane + 2];
    float* __restrict__ ob = out + (size_t)img * 262144
                           + (size_t)(by * TYO + Lr0) * 512 + bx * TXO + lane;

    float acc[8];    // per-output-row accumulators (const-indexed only)

#define LOG1(s) __builtin_amdgcn_logf(fmaxf((s), 0.0f) + 1.0f)

    // ---------------- PASS A: k = 6 and 5 (staged rows 0..12) ----------------
    {
        float h6[6], h5[5];  // rings, all indices ICEs

#define PA_ROW(i) { \
            const float* row = base + (i) * LDSW; \
            float v0 = row[0], v1 = row[1], v2 = row[2], \
                  v3 = row[3], v4 = row[4], v5 = row[5]; \
            float s05 = v0 + v5, s14 = v1 + v4, s23 = v2 + v3; \
            float s04 = v0 + v4, s13 = v1 + v3; \
            h6[(i) % 6] = W.h6a * s05 + W.h6b * s14 + W.h6c * s23; \
            h5[(i) % 5] = W.h5a * s04 + W.h5b * s13 + W.h5c * v2; \
        }
#define ITERA(r) { \
            const float* row = base + ((r) + 5) * LDSW; \
            float v0 = row[0], v1 = row[1], v2 = row[2], \
                  v3 = row[3], v4 = row[4], v5 = row[5]; \
            float s05 = v0 + v5, s14 = v1 + v4, s23 = v2 + v3; \
            float s04 = v0 + v4, s13 = v1 + v3; \
            h6[((r) + 5) % 6] = W.h6a * s05 + W.h6b * s14 + W.h6c * s23; \
            float t6 = W.v6a * (h6[(r) % 6] + h6[((r) + 5) % 6]) \
                     + W.v6b * (h6[((r) + 1) % 6] + h6[((r) + 4) % 6]) \
                     + W.v6c * (h6[((r) + 2) % 6] + h6[((r) + 3) % 6]); \
            float t5 = W.v5a * (h5[(r) % 5] + h5[((r) + 4) % 5]) \
                     + W.v5b * (h5[((r) + 1) % 5] + h5[((r) + 3) % 5]) \
                     + W.v5c * h5[((r) + 2) % 5]; \
            h5[((r) + 5) % 5] = W.h5a * s04 + W.h5b * s13 + W.h5c * v2; \
            acc[(r)] = fmaf(W.c[5], LOG1(t6), W.c[4] * LOG1(t5)); \
        }
        PA_ROW(0) PA_ROW(1) PA_ROW(2) PA_ROW(3) PA_ROW(4)
        ITERA(0) ITERA(1) ITERA(2) ITERA(3)
        ITERA(4) ITERA(5) ITERA(6) ITERA(7)
#undef PA_ROW
#undef ITERA
    }

    // ---------------- PASS B: k = 4 and 3 (staged rows 1..11) ----------------
    {
        float h4[4], h3[3];

#define PB_ROW(i) { \
            const float* row = base + (i) * LDSW; \
            float v1 = row[1], v2 = row[2], v3 = row[3], v4 = row[4]; \
            float s14 = v1 + v4, s23 = v2 + v3, s13 = v1 + v3; \
            h4[(i) % 4] = W.h4a * s14 + W.h4b * s23; \
            h3[(i) % 3] = W.h3a * s13 + W.h3b * v2; \
        }
#define ITERB(r) { \
            const float* row = base + ((r) + 4) * LDSW; \
            float v1 = row[1], v2 = row[2], v3 = row[3], v4 = row[4]; \
            float s14 = v1 + v4, s23 = v2 + v3, s13 = v1 + v3; \
            h4[((r) + 4) % 4] = W.h4a * s14 + W.h4b * s23; \
            float t4 = W.v4a * (h4[((r) + 1) % 4] + h4[((r) + 4) % 4]) \
                     + W.v4b * (h4[((r) + 2) % 4] + h4[((r) + 3) % 4]); \
            float t3 = W.v3a * (h3[((r) + 1) % 3] + h3[((r) + 3) % 3]) \
                     + W.v3b * h3[((r) + 2) % 3]; \
            h3[((r) + 4) % 3] = W.h3a * s13 + W.h3b * v2; \
            acc[(r)] = fmaf(W.c[3], LOG1(t4), fmaf(W.c[2], LOG1(t3), acc[(r)])); \
        }
        PB_ROW(1) PB_ROW(2) PB_ROW(3)
        ITERB(0) ITERB(1) ITERB(2) ITERB(3)
        ITERB(4) ITERB(5) ITERB(6) ITERB(7)
#undef PB_ROW
#undef ITERB
    }

    // ------------- PASS C: k = 2 and 1 (staged rows 2..10) + store -----------
    {
        float h2[2], h1[2];

#define PC_ROW(i) { \
            const float* row = base + (i) * LDSW; \
            float v2 = row[2], v3 = row[3]; \
            h2[(i) % 2] = W.h2c * (v2 + v3); \
            h1[(i) % 2] = v2; \
        }
#define ITERC(r) { \
            const float* row = base + ((r) + 3) * LDSW; \
            float v2 = row[2], v3 = row[3]; \
            float t1 = h1[((r) + 2) % 2]; \
            h2[((r) + 3) % 2] = W.h2c * (v2 + v3); \
            h1[((r) + 3) % 2] = v2; \
            float t2 = W.v2a * (h2[((r) + 2) % 2] + h2[((r) + 3) % 2]); \
            float res = fmaf(W.c[1], LOG1(t2), fmaf(W.c[0], LOG1(t1), acc[(r)])); \
            ob[(r) * 512] = res; \
        }
        PC_ROW(2)
        ITERC(0) ITERC(1) ITERC(2) ITERC(3)
        ITERC(4) ITERC(5) ITERC(6) ITERC(7)
#undef PC_ROW
#undef ITERC
    }
#undef LOG1
}

extern "C" void kernel_launch(void* const* d_in, const int* in_sizes, int n_in,
                              void* d_out, int out_size, void* d_ws, size_t ws_size,
                              hipStream_t stream) {
    const float* x = (const float*)d_in[0];
    float* out = (float*)d_out;

    Weights W;
    // regression coefficients: c_k = (X_k - mean(X)) / sum((X - mean)^2), X_k = log2(k)
    double X[6], mean = 0.0;
    for (int k = 1; k <= 6; ++k) { X[k - 1] = log2((double)k); mean += X[k - 1]; }
    mean /= 6.0;
    double denom = 0.0;
    for (int i = 0; i < 6; ++i) { double xc = X[i] - mean; denom += xc * xc; }
    for (int i = 0; i < 6; ++i) W.c[i] = (float)((X[i] - mean) / denom);

    // separable gaussian 1D weights, sigma = k/2
    float wh[6][6], wv[6][6];
    for (int k = 1; k <= 6; ++k) {
        double sigma = k / 2.0;
        double g[6], s = 0.0;
        for (int i = 0; i < k; ++i) {
            double a = i - (k - 1) / 2.0;
            g[i] = exp(-(a * a) / (2.0 * sigma * sigma));
            s += g[i];
        }
        for (int i = 0; i < 6; ++i) {
            if (i < k) {
                double gn = g[i] / s;
                wv[k - 1][i] = (float)gn;
                wh[k - 1][i] = (float)(gn * (double)(k * k)); // horizontal prescaled by k^2
            } else {
                wv[k - 1][i] = 0.0f;
                wh[k - 1][i] = 0.0f;
            }
        }
    }
    // symmetric-pair coefficients
    W.h6a = wh[5][0]; W.h6b = wh[5][1]; W.h6c = wh[5][2];
    W.h5a = wh[4][0]; W.h5b = wh[4][1]; W.h5c = wh[4][2];
    W.h4a = wh[3][0]; W.h4b = wh[3][1];
    W.h3a = wh[2][0]; W.h3b = wh[2][1];
    W.h2c = wh[1][0];
    W.v6a = wv[5][0]; W.v6b = wv[5][1]; W.v6c = wv[5][2];
    W.v5a = wv[4][0]; W.v5b = wv[4][1]; W.v5c = wv[4][2];
    W.v4a = wv[3][0]; W.v4b = wv[3][1];
    W.v3a = wv[2][0]; W.v3b = wv[2][1];
    W.v2a = wv[1][0];

    dim3 grid(512 / TXO, 512 / TYO, 64);
    dim3 block(64, 4, 1);
    hipLaunchKernelGGL(ldeb_kernel, grid, block, 0, stream, x, out, W);
}

// Round 10
// 43.313 us; speedup vs baseline: 1.1364x; 1.0827x over previous
//
#include <hip/hip_runtime.h>
#include <math.h>

// densemap = sum_k c_k * log2(relu(k^2 * conv_k(x)) + 1)
// conv_k = separable Gaussian (sigma = k/2), TF-SAME padding: pad_lo = (k-1)/2.
// Column/row window offsets union: -2..+3 (6 wide). k=1 kernel == identity.
//
// Tile: 64x32 outputs per block (block 64x4, 8 rows/wave), staged 37x72 LDS.
// SINGLE PASS with MINIMUM-DEPTH per-kernel rings:
//   h6[6] h5[5] h4[4] h3[4] h2[3] h1[3] = 25 floats (vs 36 for Hr[6][6]).
// No cross-phase accumulator; each output row computed+stored in its step.
// Live set ~45-50 floats -> fits the 64-reg tier at 8 waves/SIMD without
// AGPR-shuttling (R6's 2x VALU bloat) or scratch spills (R9's 90MB writes).
//
// Ring schedule at step r (after reading staged row j=r+5):
//   h6 holds rows r-1..r+4 (use fresh H6 for r+5), h5 holds r..r+4,
//   h4 holds r+1..r+4, h3(d4) holds r+1..r+4, h2(d3) holds r+2..r+4,
//   h1(d3) slot (r+5)%3 still holds row r+2. All tap sets covered; all
//   reads precede conflicting writes.

struct Weights {
    // horizontal symmetric-pair coefficients (prescaled by k^2)
    float h6a, h6b, h6c, h5a, h5b, h5c, h4a, h4b, h3a, h3b, h2c;
    // vertical symmetric-pair coefficients
    float v6a, v6b, v6c, v5a, v5b, v5c, v4a, v4b, v3a, v3b, v2a;
    float c[6];     // regression slope coefficients
};

#define TXO 64
#define TYO 32
#define RPT 8           // rows per thread (block 64x4)
#define LDSW 72         // floats per staged row (16B-aligned stride)
#define SROWS 37        // staged rows: outputs -2..+34
#define NF4 (SROWS * 18)  // 666 float4s per tile

#define GLOAD_LDS16(gp, lp) __builtin_amdgcn_global_load_lds( \
    (const __attribute__((address_space(1))) unsigned int*)(gp), \
    (__attribute__((address_space(3))) unsigned int*)(lp), 16, 0, 0)

__global__ __launch_bounds__(256, 8) void ldeb_kernel(const float* __restrict__ x,
                                                      float* __restrict__ out,
                                                      Weights W) {
    __shared__ float xs[SROWS * LDSW];
    const int img = blockIdx.z;
    const int bx = blockIdx.x, by = blockIdx.y;
    const int x0a = bx * TXO - 4;      // aligned staged-col base
    const int y0 = by * TYO - 2;       // staged-row base
    const float* __restrict__ xb = x + (size_t)img * 262144;
    const int tid = threadIdx.y * 64 + threadIdx.x;

    if (bx >= 1 && bx <= 6 && by >= 1 && by <= 14) {
        // interior: direct global->LDS, 16B/lane, dest linear in tid
#pragma unroll
        for (int it = 0; it < 3; ++it) {
            int i = tid + it * 256;
            if (i < NF4) {
                int row = i / 18;
                int c4 = i - row * 18;
                const float* gp = xb + (size_t)(y0 + row) * 512 + x0a + 4 * c4;
                GLOAD_LDS16(gp, &xs[i * 4]);
            }
        }
    } else {
        // border: reg-staged float4 with whole-float4 zero-fill
#pragma unroll
        for (int it = 0; it < 3; ++it) {
            int i = tid + it * 256;
            if (i < NF4) {
                int row = i / 18;
                int c4 = i - row * 18;
                int gy = y0 + row;
                int gc = x0a + 4 * c4;
                float4 v = make_float4(0.f, 0.f, 0.f, 0.f);
                if ((unsigned)gy < 512u && (unsigned)gc < 512u)
                    v = *(const float4*)(xb + (size_t)gy * 512 + gc);
                *(float4*)&xs[i * 4] = v;
            }
        }
    }
    __syncthreads();

    const int lane = threadIdx.x;        // local col 0..63
    const int Lr0 = threadIdx.y * RPT;   // this wave's staged-row base
    const float* __restrict__ base = &xs[Lr0 * LDSW + lane + 2];
    float* __restrict__ ob = out + (size_t)img * 262144
                           + (size_t)(by * TYO + Lr0) * 512 + bx * TXO + lane;

    float h6[6], h5[5], h4[4], h3[4], h2[3], h1[3];  // all indices ICEs

#define LOG1(s) __builtin_amdgcn_logf(fmaxf((s), 0.0f) + 1.0f)

// prologue row j = 0..4: fill rings only
#define PROW(j) { \
        const float* row = base + (j) * LDSW; \
        float v0 = row[0], v1 = row[1], v2 = row[2], \
              v3 = row[3], v4 = row[4], v5 = row[5]; \
        float s05 = v0 + v5, s14 = v1 + v4, s23 = v2 + v3; \
        float s04 = v0 + v4, s13 = v1 + v3; \
        h6[(j) % 6] = W.h6a * s05 + W.h6b * s14 + W.h6c * s23; \
        h5[(j) % 5] = W.h5a * s04 + W.h5b * s13 + W.h5c * v2; \
        h4[(j) % 4] = W.h4a * s14 + W.h4b * s23; \
        h3[(j) % 4] = W.h3a * s13 + W.h3b * v2; \
        h2[(j) % 3] = W.h2c * s23; \
        h1[(j) % 3] = v2; \
    }

// step r: read staged row r+5, emit output row r
#define STEPR(r) { \
        const float* row = base + ((r) + 5) * LDSW; \
        float v0 = row[0], v1 = row[1], v2 = row[2], \
              v3 = row[3], v4 = row[4], v5 = row[5]; \
        float s05 = v0 + v5, s14 = v1 + v4, s23 = v2 + v3; \
        float s04 = v0 + v4, s13 = v1 + v3; \
        float H6 = W.h6a * s05 + W.h6b * s14 + W.h6c * s23; \
        float t6 = W.v6a * (h6[(r) % 6] + H6) \
                 + W.v6b * (h6[((r) + 1) % 6] + h6[((r) + 4) % 6]) \
                 + W.v6c * (h6[((r) + 2) % 6] + h6[((r) + 3) % 6]); \
        float t5 = W.v5a * (h5[(r) % 5] + h5[((r) + 4) % 5]) \
                 + W.v5b * (h5[((r) + 1) % 5] + h5[((r) + 3) % 5]) \
                 + W.v5c * h5[((r) + 2) % 5]; \
        float t4 = W.v4a * (h4[((r) + 1) % 4] + h4[((r) + 4) % 4]) \
                 + W.v4b * (h4[((r) + 2) % 4] + h4[((r) + 3) % 4]); \
        float t3 = W.v3a * (h3[((r) + 1) % 4] + h3[((r) + 3) % 4]) \
                 + W.v3b * h3[((r) + 2) % 4]; \
        float t2 = W.v2a * (h2[((r) + 2) % 3] + h2[((r) + 3) % 3]); \
        float t1 = h1[((r) + 5) % 3]; /* row r+2, read before overwrite */ \
        h6[((r) + 5) % 6] = H6; \
        h5[((r) + 5) % 5] = W.h5a * s04 + W.h5b * s13 + W.h5c * v2; \
        h4[((r) + 5) % 4] = W.h4a * s14 + W.h4b * s23; \
        h3[((r) + 5) % 4] = W.h3a * s13 + W.h3b * v2; \
        h2[((r) + 5) % 3] = W.h2c * s23; \
        h1[((r) + 5) % 3] = v2; \
        float res = fmaf(W.c[5], LOG1(t6), \
                    fmaf(W.c[4], LOG1(t5), \
                    fmaf(W.c[3], LOG1(t4), \
                    fmaf(W.c[2], LOG1(t3), \
                    fmaf(W.c[1], LOG1(t2), \
                         W.c[0] * LOG1(t1)))))); \
        ob[(r) * 512] = res; \
    }

    PROW(0) PROW(1) PROW(2) PROW(3) PROW(4)
    STEPR(0) STEPR(1) STEPR(2) STEPR(3)
    STEPR(4) STEPR(5) STEPR(6) STEPR(7)

#undef STEPR
#undef PROW
#undef LOG1
}

extern "C" void kernel_launch(void* const* d_in, const int* in_sizes, int n_in,
                              void* d_out, int out_size, void* d_ws, size_t ws_size,
                              hipStream_t stream) {
    const float* x = (const float*)d_in[0];
    float* out = (float*)d_out;

    Weights W;
    // regression coefficients: c_k = (X_k - mean(X)) / sum((X - mean)^2), X_k = log2(k)
    double X[6], mean = 0.0;
    for (int k = 1; k <= 6; ++k) { X[k - 1] = log2((double)k); mean += X[k - 1]; }
    mean /= 6.0;
    double denom = 0.0;
    for (int i = 0; i < 6; ++i) { double xc = X[i] - mean; denom += xc * xc; }
    for (int i = 0; i < 6; ++i) W.c[i] = (float)((X[i] - mean) / denom);

    // separable gaussian 1D weights, sigma = k/2
    float wh[6][6], wv[6][6];
    for (int k = 1; k <= 6; ++k) {
        double sigma = k / 2.0;
        double g[6], s = 0.0;
        for (int i = 0; i < k; ++i) {
            double a = i - (k - 1) / 2.0;
            g[i] = exp(-(a * a) / (2.0 * sigma * sigma));
            s += g[i];
        }
        for (int i = 0; i < 6; ++i) {
            if (i < k) {
                double gn = g[i] / s;
                wv[k - 1][i] = (float)gn;
                wh[k - 1][i] = (float)(gn * (double)(k * k)); // horizontal prescaled by k^2
            } else {
                wv[k - 1][i] = 0.0f;
                wh[k - 1][i] = 0.0f;
            }
        }
    }
    // symmetric-pair coefficients
    W.h6a = wh[5][0]; W.h6b = wh[5][1]; W.h6c = wh[5][2];
    W.h5a = wh[4][0]; W.h5b = wh[4][1]; W.h5c = wh[4][2];
    W.h4a = wh[3][0]; W.h4b = wh[3][1];
    W.h3a = wh[2][0]; W.h3b = wh[2][1];
    W.h2c = wh[1][0];
    W.v6a = wv[5][0]; W.v6b = wv[5][1]; W.v6c = wv[5][2];
    W.v5a = wv[4][0]; W.v5b = wv[4][1]; W.v5c = wv[4][2];
    W.v4a = wv[3][0]; W.v4b = wv[3][1];
    W.v3a = wv[2][0]; W.v3b = wv[2][1];
    W.v2a = wv[1][0];

    dim3 grid(512 / TXO, 512 / TYO, 64);
    dim3 block(64, 4, 1);
    hipLaunchKernelGGL(ldeb_kernel, grid, block, 0, stream, x, out, W);
}